// Round 1
// baseline (534.950 us; speedup 1.0000x reference)
//
#include <hip/hip_runtime.h>
#include <cmath>

#define N_NODES 50000
#define N_EDGES 800000
#define N_FEAT 128
#define DIM 64
#define N_GRAPHS 512

// ---------------------------------------------------------------------------
// zero-fill (ws is re-poisoned to 0xAA before every timed launch)
__global__ __launch_bounds__(256) void zero_f4(float4* __restrict__ p, int n4) {
  int i = blockIdx.x * 256 + threadIdx.x;
  if (i < n4) p[i] = make_float4(0.f, 0.f, 0.f, 0.f);
}

// ---------------------------------------------------------------------------
// out[M][64] = act(A[M][K]) @ W[K][64]   (RELU applied to A on load)
// Register-tiled fp32 GEMM: 64-row x 64-col block tile, 4x4 per thread.
// LDS: sX padded to XP=K+4 floats/row -> 16B-aligned float4 reads, and
// 4-row stride (4*XP)%32==16 banks -> only 2-way conflicts (free on gfx950).
// W staged in 64-k chunks to stay under the 64 KB LDS/workgroup limit.
template<int K, bool RELU>
__global__ __launch_bounds__(256) void gemm_n64(const float* __restrict__ A,
                                                const float* __restrict__ W,
                                                float* __restrict__ out, int M) {
  constexpr int XP = K + 4;
  __shared__ float sX[64 * XP];
  __shared__ float sW[64 * 64];
  const int tid = threadIdx.x;
  const int row0 = blockIdx.x * 64;

  for (int i = tid; i < 64 * K; i += 256) {
    int r = i / K, c = i - r * K;
    int gr = row0 + r;
    float v = (gr < M) ? A[(size_t)gr * K + c] : 0.f;
    if (RELU) v = fmaxf(v, 0.f);
    sX[r * XP + c] = v;
  }

  const int tx = tid & 15, ty = tid >> 4;
  float acc[4][4] = {};

  for (int kb = 0; kb < K; kb += 64) {
    __syncthreads();                       // sX ready / sW consumers done
    for (int i = tid; i < 64 * 64; i += 256) sW[i] = W[kb * 64 + i];
    __syncthreads();
#pragma unroll 4
    for (int k = 0; k < 64; k += 4) {
      float4 wv[4];
#pragma unroll
      for (int kk = 0; kk < 4; kk++)
        wv[kk] = *(const float4*)&sW[(k + kk) * 64 + tx * 4];
#pragma unroll
      for (int r = 0; r < 4; r++) {
        float4 xv = *(const float4*)&sX[(ty * 4 + r) * XP + kb + k];
        const float xs[4] = {xv.x, xv.y, xv.z, xv.w};
#pragma unroll
        for (int kk = 0; kk < 4; kk++) {
          acc[r][0] += xs[kk] * wv[kk].x;
          acc[r][1] += xs[kk] * wv[kk].y;
          acc[r][2] += xs[kk] * wv[kk].z;
          acc[r][3] += xs[kk] * wv[kk].w;
        }
      }
    }
  }

#pragma unroll
  for (int r = 0; r < 4; r++) {
    int gr = row0 + ty * 4 + r;
    if (gr < M)
      *(float4*)&out[(size_t)gr * 64 + tx * 4] =
          make_float4(acc[r][0], acc[r][1], acc[r][2], acc[r][3]);
  }
}

// ---------------------------------------------------------------------------
// agg[dst[e]][f] += h[src[e]][f]   one thread per (edge, feature)
// Wave = one edge: coalesced 256B gather of h[src], 64 consecutive atomics.
__global__ __launch_bounds__(256) void scatter_add(const float* __restrict__ h,
                                                   const int* __restrict__ src,
                                                   const int* __restrict__ dst,
                                                   float* __restrict__ agg) {
  long long gid = (long long)blockIdx.x * 256 + threadIdx.x;
  int e = (int)(gid >> 6);
  if (e >= N_EDGES) return;
  int f = (int)(gid & 63);
  int s = src[e], d = dst[e];
  atomicAdd(&agg[(size_t)d * 64 + f], h[(size_t)s * 64 + f]);
}

// ---------------------------------------------------------------------------
// batch is SORTED -> per-graph contiguous segment. One 64-thread block per
// graph: binary-search [start,end), sum rows, mean, fused FC (64x1) + sigmoid.
__global__ __launch_bounds__(64) void pool_fc(const float* __restrict__ agg,
                                              const int* __restrict__ batch,
                                              const float* __restrict__ Wfc,
                                              float* __restrict__ out) {
  int g = blockIdx.x;
  int lane = threadIdx.x;

  int lo = 0, hi = N_NODES;
  while (lo < hi) { int mid = (lo + hi) >> 1; if (batch[mid] < g) lo = mid + 1; else hi = mid; }
  const int start = lo;
  hi = N_NODES;
  while (lo < hi) { int mid = (lo + hi) >> 1; if (batch[mid] < g + 1) lo = mid + 1; else hi = mid; }
  const int end = lo;

  float acc = 0.f;
  for (int n = start; n < end; n++) acc += agg[(size_t)n * 64 + lane];
  acc /= fmaxf((float)(end - start), 1.f);

  float v = acc * Wfc[lane];
#pragma unroll
  for (int off = 32; off; off >>= 1) v += __shfl_down(v, off, 64);
  if (lane == 0) out[g] = 1.f / (1.f + expf(-v));
}

// ---------------------------------------------------------------------------
extern "C" void kernel_launch(void* const* d_in, const int* in_sizes, int n_in,
                              void* d_out, int out_size, void* d_ws, size_t ws_size,
                              hipStream_t stream) {
  const float* x     = (const float*)d_in[0];
  const int*   ei    = (const int*)d_in[1];   // [2, E]: src then dst
  const int*   batch = (const int*)d_in[2];
  const float* W1    = (const float*)d_in[3];
  const float* W2    = (const float*)d_in[4];
  const float* Wfc   = (const float*)d_in[5];
  float*       out   = (float*)d_out;

  const int* src = ei;
  const int* dst = ei + N_EDGES;

  float* h   = (float*)d_ws;                       // [N, 64]
  float* agg = h + (size_t)N_NODES * DIM;          // [N, 64]

  const int n4 = N_NODES * DIM / 4;
  const int zgrid = (n4 + 255) / 256;
  const int ggrid = (N_NODES + 63) / 64;
  const int sgrid = (int)(((long long)N_EDGES * 64) / 256);

  // layer 1: h = x @ W1 ; agg = scatter_add(h[src] -> dst)
  zero_f4<<<zgrid, 256, 0, stream>>>((float4*)agg, n4);
  gemm_n64<N_FEAT, false><<<ggrid, 256, 0, stream>>>(x, W1, h, N_NODES);
  scatter_add<<<sgrid, 256, 0, stream>>>(h, src, dst, agg);

  // layer 2: h = relu(agg) @ W2 ; agg = scatter_add(h[src] -> dst)
  gemm_n64<DIM, true><<<ggrid, 256, 0, stream>>>(agg, W2, h, N_NODES);
  zero_f4<<<zgrid, 256, 0, stream>>>((float4*)agg, n4);
  scatter_add<<<sgrid, 256, 0, stream>>>(h, src, dst, agg);

  // mean-pool per graph + FC + sigmoid
  pool_fc<<<N_GRAPHS, 64, 0, stream>>>(agg, batch, Wfc, out);
}

// Round 2
// 464.947 us; speedup vs baseline: 1.1506x; 1.1506x over previous
//
#include <hip/hip_runtime.h>
#include <cmath>

#define N_NODES 50000
#define N_EDGES 800000
#define N_FEAT 128
#define DIM 64
#define N_GRAPHS 512

// ---------------------------------------------------------------------------
// zero-fill ints (ws is re-poisoned to 0xAA before every timed launch)
__global__ __launch_bounds__(256) void zero_i(int* __restrict__ p, int n) {
  int i = blockIdx.x * 256 + threadIdx.x;
  if (i < n) p[i] = 0;
}

// ---------------------------------------------------------------------------
// CSR build: histogram of dst
__global__ __launch_bounds__(256) void hist_dst(const int* __restrict__ dst,
                                                int* __restrict__ deg) {
  int e = blockIdx.x * 256 + threadIdx.x;
  if (e < N_EDGES) atomicAdd(&deg[dst[e]], 1);
}

// single-block exclusive scan of deg[N_NODES] -> row_ptr[N_NODES+1], fill_pos
__global__ __launch_bounds__(1024) void scan_deg(const int* __restrict__ deg,
                                                 int* __restrict__ row_ptr,
                                                 int* __restrict__ fill_pos) {
  __shared__ int buf[1024];
  const int tid = threadIdx.x;
  const int CHUNK = (N_NODES + 1023) / 1024;           // 49
  const int base = tid * CHUNK;

  int sum = 0;
  for (int i = 0; i < CHUNK; i++) {
    int idx = base + i;
    if (idx < N_NODES) sum += deg[idx];
  }
  buf[tid] = sum;
  __syncthreads();
  // Hillis-Steele inclusive scan over 1024 partials
  for (int off = 1; off < 1024; off <<= 1) {
    int t = (tid >= off) ? buf[tid - off] : 0;
    __syncthreads();
    buf[tid] += t;
    __syncthreads();
  }
  int run = buf[tid] - sum;                            // exclusive prefix
  for (int i = 0; i < CHUNK; i++) {
    int idx = base + i;
    if (idx < N_NODES) {
      row_ptr[idx] = run;
      fill_pos[idx] = run;
      run += deg[idx];
    }
  }
  if (tid == 1023) row_ptr[N_NODES] = buf[1023];       // == N_EDGES
}

// scatter edge ids into CSR slots: col[slot] = src[e] for edges grouped by dst
__global__ __launch_bounds__(256) void fill_csr(const int* __restrict__ src,
                                                const int* __restrict__ dst,
                                                int* __restrict__ fill_pos,
                                                int* __restrict__ col) {
  int e = blockIdx.x * 256 + threadIdx.x;
  if (e >= N_EDGES) return;
  int slot = atomicAdd(&fill_pos[dst[e]], 1);
  col[slot] = src[e];
}

// ---------------------------------------------------------------------------
// out[n][f] = sum over in-edges of h[col[i]][f]. One wave per node, lane=f.
// Per edge: broadcast col load + one coalesced 256B row read (L2/L3 resident).
__global__ __launch_bounds__(256) void gather_sum(const float* __restrict__ h,
                                                  const int* __restrict__ row_ptr,
                                                  const int* __restrict__ col,
                                                  float* __restrict__ out) {
  int node = blockIdx.x * 4 + (threadIdx.x >> 6);
  if (node >= N_NODES) return;
  int lane = threadIdx.x & 63;
  int i = row_ptr[node];
  const int end = row_ptr[node + 1];

  float acc = 0.f;
  for (; i + 4 <= end; i += 4) {                       // 4-deep load pipelining
    int s0 = col[i], s1 = col[i + 1], s2 = col[i + 2], s3 = col[i + 3];
    float v0 = h[(size_t)s0 * 64 + lane];
    float v1 = h[(size_t)s1 * 64 + lane];
    float v2 = h[(size_t)s2 * 64 + lane];
    float v3 = h[(size_t)s3 * 64 + lane];
    acc += (v0 + v1) + (v2 + v3);
  }
  for (; i < end; i++) acc += h[(size_t)col[i] * 64 + lane];

  out[(size_t)node * 64 + lane] = acc;
}

// ---------------------------------------------------------------------------
// out[M][64] = act(A[M][K]) @ W[K][64]   (RELU applied to A on load)
template<int K, bool RELU>
__global__ __launch_bounds__(256) void gemm_n64(const float* __restrict__ A,
                                                const float* __restrict__ W,
                                                float* __restrict__ out, int M) {
  constexpr int XP = K + 4;
  __shared__ float sX[64 * XP];
  __shared__ float sW[64 * 64];
  const int tid = threadIdx.x;
  const int row0 = blockIdx.x * 64;

  for (int i = tid; i < 64 * K; i += 256) {
    int r = i / K, c = i - r * K;
    int gr = row0 + r;
    float v = (gr < M) ? A[(size_t)gr * K + c] : 0.f;
    if (RELU) v = fmaxf(v, 0.f);
    sX[r * XP + c] = v;
  }

  const int tx = tid & 15, ty = tid >> 4;
  float acc[4][4] = {};

  for (int kb = 0; kb < K; kb += 64) {
    __syncthreads();
    for (int i = tid; i < 64 * 64; i += 256) sW[i] = W[kb * 64 + i];
    __syncthreads();
#pragma unroll 4
    for (int k = 0; k < 64; k += 4) {
      float4 wv[4];
#pragma unroll
      for (int kk = 0; kk < 4; kk++)
        wv[kk] = *(const float4*)&sW[(k + kk) * 64 + tx * 4];
#pragma unroll
      for (int r = 0; r < 4; r++) {
        float4 xv = *(const float4*)&sX[(ty * 4 + r) * XP + kb + k];
        const float xs[4] = {xv.x, xv.y, xv.z, xv.w};
#pragma unroll
        for (int kk = 0; kk < 4; kk++) {
          acc[r][0] += xs[kk] * wv[kk].x;
          acc[r][1] += xs[kk] * wv[kk].y;
          acc[r][2] += xs[kk] * wv[kk].z;
          acc[r][3] += xs[kk] * wv[kk].w;
        }
      }
    }
  }

#pragma unroll
  for (int r = 0; r < 4; r++) {
    int gr = row0 + ty * 4 + r;
    if (gr < M)
      *(float4*)&out[(size_t)gr * 64 + tx * 4] =
          make_float4(acc[r][0], acc[r][1], acc[r][2], acc[r][3]);
  }
}

// ---------------------------------------------------------------------------
// batch is SORTED -> per-graph contiguous segment. One 64-thread block per
// graph: binary-search [start,end), sum rows, mean, fused FC (64x1) + sigmoid.
__global__ __launch_bounds__(64) void pool_fc(const float* __restrict__ agg,
                                              const int* __restrict__ batch,
                                              const float* __restrict__ Wfc,
                                              float* __restrict__ out) {
  int g = blockIdx.x;
  int lane = threadIdx.x;

  int lo = 0, hi = N_NODES;
  while (lo < hi) { int mid = (lo + hi) >> 1; if (batch[mid] < g) lo = mid + 1; else hi = mid; }
  const int start = lo;
  hi = N_NODES;
  while (lo < hi) { int mid = (lo + hi) >> 1; if (batch[mid] < g + 1) lo = mid + 1; else hi = mid; }
  const int end = lo;

  float acc = 0.f;
  for (int n = start; n < end; n++) acc += agg[(size_t)n * 64 + lane];
  acc /= fmaxf((float)(end - start), 1.f);

  float v = acc * Wfc[lane];
#pragma unroll
  for (int off = 32; off; off >>= 1) v += __shfl_down(v, off, 64);
  if (lane == 0) out[g] = 1.f / (1.f + expf(-v));
}

// ---------------------------------------------------------------------------
extern "C" void kernel_launch(void* const* d_in, const int* in_sizes, int n_in,
                              void* d_out, int out_size, void* d_ws, size_t ws_size,
                              hipStream_t stream) {
  const float* x     = (const float*)d_in[0];
  const int*   ei    = (const int*)d_in[1];   // [2, E]: src then dst
  const int*   batch = (const int*)d_in[2];
  const float* W1    = (const float*)d_in[3];
  const float* W2    = (const float*)d_in[4];
  const float* Wfc   = (const float*)d_in[5];
  float*       out   = (float*)d_out;

  const int* src = ei;
  const int* dst = ei + N_EDGES;

  // workspace layout (≈29.4 MB)
  char* ws = (char*)d_ws;
  float* h        = (float*)(ws);                                   // [N,64]
  float* agg      = (float*)(ws + (size_t)N_NODES * DIM * 4);       // [N,64]
  int*   deg      = (int*)  (ws + (size_t)N_NODES * DIM * 8);
  int*   row_ptr  = deg + N_NODES;
  int*   fill_pos = row_ptr + N_NODES + 1;
  int*   col      = fill_pos + N_NODES;                             // [E]

  const int egrid = (N_EDGES + 255) / 256;
  const int ggrid = (N_NODES + 63) / 64;
  const int ngrid4 = (N_NODES + 3) / 4;

  // CSR build (shared by both layers)
  zero_i<<<(N_NODES + 255) / 256, 256, 0, stream>>>(deg, N_NODES);
  hist_dst<<<egrid, 256, 0, stream>>>(dst, deg);
  scan_deg<<<1, 1024, 0, stream>>>(deg, row_ptr, fill_pos);
  fill_csr<<<egrid, 256, 0, stream>>>(src, dst, fill_pos, col);

  // layer 1: h = x @ W1 ; agg = gather_sum(h)
  gemm_n64<N_FEAT, false><<<ggrid, 256, 0, stream>>>(x, W1, h, N_NODES);
  gather_sum<<<ngrid4, 256, 0, stream>>>(h, row_ptr, col, agg);

  // layer 2: h = relu(agg) @ W2 ; agg = gather_sum(h)
  gemm_n64<DIM, true><<<ggrid, 256, 0, stream>>>(agg, W2, h, N_NODES);
  gather_sum<<<ngrid4, 256, 0, stream>>>(h, row_ptr, col, agg);

  // mean-pool per graph + FC + sigmoid
  pool_fc<<<N_GRAPHS, 64, 0, stream>>>(agg, batch, Wfc, out);
}

// Round 3
// 350.324 us; speedup vs baseline: 1.5270x; 1.3272x over previous
//
#include <hip/hip_runtime.h>
#include <cmath>

#define N_NODES 50000
#define N_EDGES 800000
#define N_FEAT 128
#define DIM 64
#define N_GRAPHS 512
#define SCAN_NBLK ((N_NODES + 255) / 256)   // 196

// ---------------------------------------------------------------------------
// zero-fill ints (ws is re-poisoned to 0xAA before every timed launch)
__global__ __launch_bounds__(256) void zero_i(int* __restrict__ p, int n) {
  int i = blockIdx.x * 256 + threadIdx.x;
  if (i < n) p[i] = 0;
}

// ---------------------------------------------------------------------------
// CSR build: histogram of dst
__global__ __launch_bounds__(256) void hist_dst(const int* __restrict__ dst,
                                                int* __restrict__ deg) {
  int e = blockIdx.x * 256 + threadIdx.x;
  if (e < N_EDGES) atomicAdd(&deg[dst[e]], 1);
}

// ---------------------------------------------------------------------------
// hierarchical exclusive scan of deg[N_NODES] -> row_ptr[N_NODES+1], fill_pos
// pass 1: per-block sums
__global__ __launch_bounds__(256) void partial_sums(const int* __restrict__ deg,
                                                    int* __restrict__ partials) {
  __shared__ int ws[4];
  int gid = blockIdx.x * 256 + threadIdx.x;
  int v = (gid < N_NODES) ? deg[gid] : 0;
#pragma unroll
  for (int off = 32; off; off >>= 1) v += __shfl_down(v, off, 64);
  int lane = threadIdx.x & 63, w = threadIdx.x >> 6;
  if (lane == 0) ws[w] = v;
  __syncthreads();
  if (threadIdx.x == 0)
    partials[blockIdx.x] = ws[0] + ws[1] + ws[2] + ws[3];
}

// pass 2: single block scans the 196 partials in-place -> exclusive offsets
__global__ __launch_bounds__(256) void scan_partials(int* __restrict__ partials) {
  __shared__ int buf[256];
  int tid = threadIdx.x;
  int v = (tid < SCAN_NBLK) ? partials[tid] : 0;
  buf[tid] = v;
  __syncthreads();
  for (int off = 1; off < 256; off <<= 1) {
    int t = (tid >= off) ? buf[tid - off] : 0;
    __syncthreads();
    buf[tid] += t;
    __syncthreads();
  }
  if (tid < SCAN_NBLK) partials[tid] = buf[tid] - v;   // exclusive
}

// pass 3: block-local exclusive scan + block offset -> row_ptr, fill_pos
__global__ __launch_bounds__(256) void scan_blocks(const int* __restrict__ deg,
                                                   const int* __restrict__ partials,
                                                   int* __restrict__ row_ptr,
                                                   int* __restrict__ fill_pos) {
  __shared__ int buf[256];
  int tid = threadIdx.x;
  int gid = blockIdx.x * 256 + tid;
  int v = (gid < N_NODES) ? deg[gid] : 0;
  buf[tid] = v;
  __syncthreads();
  for (int off = 1; off < 256; off <<= 1) {
    int t = (tid >= off) ? buf[tid - off] : 0;
    __syncthreads();
    buf[tid] += t;
    __syncthreads();
  }
  int excl = buf[tid] - v + partials[blockIdx.x];
  if (gid <= N_NODES) {                 // gid==N_NODES writes row_ptr[N]=E
    row_ptr[gid] = excl;
    if (gid < N_NODES) fill_pos[gid] = excl;
  }
}

// scatter edge ids into CSR slots: col[slot] = src[e] for edges grouped by dst
__global__ __launch_bounds__(256) void fill_csr(const int* __restrict__ src,
                                                const int* __restrict__ dst,
                                                int* __restrict__ fill_pos,
                                                int* __restrict__ col) {
  int e = blockIdx.x * 256 + threadIdx.x;
  if (e >= N_EDGES) return;
  int slot = atomicAdd(&fill_pos[dst[e]], 1);
  col[slot] = src[e];
}

// ---------------------------------------------------------------------------
// out[n][f] = sum over in-edges of h[col[i]][f]. One wave per node, lane=f.
// Per edge: broadcast col load + one coalesced 256B row read (L2/L3 resident).
__global__ __launch_bounds__(256) void gather_sum(const float* __restrict__ h,
                                                  const int* __restrict__ row_ptr,
                                                  const int* __restrict__ col,
                                                  float* __restrict__ out) {
  int node = blockIdx.x * 4 + (threadIdx.x >> 6);
  if (node >= N_NODES) return;
  int lane = threadIdx.x & 63;
  int i = row_ptr[node];
  const int end = row_ptr[node + 1];

  float acc = 0.f;
  for (; i + 4 <= end; i += 4) {                       // 4-deep load pipelining
    int s0 = col[i], s1 = col[i + 1], s2 = col[i + 2], s3 = col[i + 3];
    float v0 = h[(size_t)s0 * 64 + lane];
    float v1 = h[(size_t)s1 * 64 + lane];
    float v2 = h[(size_t)s2 * 64 + lane];
    float v3 = h[(size_t)s3 * 64 + lane];
    acc += (v0 + v1) + (v2 + v3);
  }
  for (; i < end; i++) acc += h[(size_t)col[i] * 64 + lane];

  out[(size_t)node * 64 + lane] = acc;
}

// ---------------------------------------------------------------------------
// out[M][64] = act(A[M][K]) @ W[K][64]   (RELU applied to A on load)
template<int K, bool RELU>
__global__ __launch_bounds__(256) void gemm_n64(const float* __restrict__ A,
                                                const float* __restrict__ W,
                                                float* __restrict__ out, int M) {
  constexpr int XP = K + 4;
  __shared__ float sX[64 * XP];
  __shared__ float sW[64 * 64];
  const int tid = threadIdx.x;
  const int row0 = blockIdx.x * 64;

  for (int i = tid; i < 64 * K; i += 256) {
    int r = i / K, c = i - r * K;
    int gr = row0 + r;
    float v = (gr < M) ? A[(size_t)gr * K + c] : 0.f;
    if (RELU) v = fmaxf(v, 0.f);
    sX[r * XP + c] = v;
  }

  const int tx = tid & 15, ty = tid >> 4;
  float acc[4][4] = {};

  for (int kb = 0; kb < K; kb += 64) {
    __syncthreads();
    for (int i = tid; i < 64 * 64; i += 256) sW[i] = W[kb * 64 + i];
    __syncthreads();
#pragma unroll 4
    for (int k = 0; k < 64; k += 4) {
      float4 wv[4];
#pragma unroll
      for (int kk = 0; kk < 4; kk++)
        wv[kk] = *(const float4*)&sW[(k + kk) * 64 + tx * 4];
#pragma unroll
      for (int r = 0; r < 4; r++) {
        float4 xv = *(const float4*)&sX[(ty * 4 + r) * XP + kb + k];
        const float xs[4] = {xv.x, xv.y, xv.z, xv.w};
#pragma unroll
        for (int kk = 0; kk < 4; kk++) {
          acc[r][0] += xs[kk] * wv[kk].x;
          acc[r][1] += xs[kk] * wv[kk].y;
          acc[r][2] += xs[kk] * wv[kk].z;
          acc[r][3] += xs[kk] * wv[kk].w;
        }
      }
    }
  }

#pragma unroll
  for (int r = 0; r < 4; r++) {
    int gr = row0 + ty * 4 + r;
    if (gr < M)
      *(float4*)&out[(size_t)gr * 64 + tx * 4] =
          make_float4(acc[r][0], acc[r][1], acc[r][2], acc[r][3]);
  }
}

// ---------------------------------------------------------------------------
// batch is SORTED -> per-graph contiguous segment. One 64-thread block per
// graph: binary-search [start,end), sum rows, mean, fused FC (64x1) + sigmoid.
__global__ __launch_bounds__(64) void pool_fc(const float* __restrict__ agg,
                                              const int* __restrict__ batch,
                                              const float* __restrict__ Wfc,
                                              float* __restrict__ out) {
  int g = blockIdx.x;
  int lane = threadIdx.x;

  int lo = 0, hi = N_NODES;
  while (lo < hi) { int mid = (lo + hi) >> 1; if (batch[mid] < g) lo = mid + 1; else hi = mid; }
  const int start = lo;
  hi = N_NODES;
  while (lo < hi) { int mid = (lo + hi) >> 1; if (batch[mid] < g + 1) lo = mid + 1; else hi = mid; }
  const int end = lo;

  float acc = 0.f;
  for (int n = start; n < end; n++) acc += agg[(size_t)n * 64 + lane];
  acc /= fmaxf((float)(end - start), 1.f);

  float v = acc * Wfc[lane];
#pragma unroll
  for (int off = 32; off; off >>= 1) v += __shfl_down(v, off, 64);
  if (lane == 0) out[g] = 1.f / (1.f + expf(-v));
}

// ---------------------------------------------------------------------------
extern "C" void kernel_launch(void* const* d_in, const int* in_sizes, int n_in,
                              void* d_out, int out_size, void* d_ws, size_t ws_size,
                              hipStream_t stream) {
  const float* x     = (const float*)d_in[0];
  const int*   ei    = (const int*)d_in[1];   // [2, E]: src then dst
  const int*   batch = (const int*)d_in[2];
  const float* W1    = (const float*)d_in[3];
  const float* W2    = (const float*)d_in[4];
  const float* Wfc   = (const float*)d_in[5];
  float*       out   = (float*)d_out;

  const int* src = ei;
  const int* dst = ei + N_EDGES;

  // workspace layout (≈29.4 MB)
  char* ws = (char*)d_ws;
  float* h        = (float*)(ws);                                   // [N,64]
  float* agg      = (float*)(ws + (size_t)N_NODES * DIM * 4);       // [N,64]
  int*   deg      = (int*)  (ws + (size_t)N_NODES * DIM * 8);
  int*   row_ptr  = deg + N_NODES;
  int*   fill_pos = row_ptr + N_NODES + 1;
  int*   col      = fill_pos + N_NODES;                             // [E]
  int*   partials = col + N_EDGES;                                  // [196]

  const int egrid = (N_EDGES + 255) / 256;
  const int ggrid = (N_NODES + 63) / 64;
  const int ngrid4 = (N_NODES + 3) / 4;

  // CSR build (shared by both layers)
  zero_i<<<(N_NODES + 255) / 256, 256, 0, stream>>>(deg, N_NODES);
  hist_dst<<<egrid, 256, 0, stream>>>(dst, deg);
  partial_sums<<<SCAN_NBLK, 256, 0, stream>>>(deg, partials);
  scan_partials<<<1, 256, 0, stream>>>(partials);
  scan_blocks<<<SCAN_NBLK, 256, 0, stream>>>(deg, partials, row_ptr, fill_pos);
  fill_csr<<<egrid, 256, 0, stream>>>(src, dst, fill_pos, col);

  // layer 1: h = x @ W1 ; agg = gather_sum(h)
  gemm_n64<N_FEAT, false><<<ggrid, 256, 0, stream>>>(x, W1, h, N_NODES);
  gather_sum<<<ngrid4, 256, 0, stream>>>(h, row_ptr, col, agg);

  // layer 2: h = relu(agg) @ W2 ; agg = gather_sum(h)
  gemm_n64<DIM, true><<<ggrid, 256, 0, stream>>>(agg, W2, h, N_NODES);
  gather_sum<<<ngrid4, 256, 0, stream>>>(h, row_ptr, col, agg);

  // mean-pool per graph + FC + sigmoid
  pool_fc<<<N_GRAPHS, 64, 0, stream>>>(agg, batch, Wfc, out);
}

// Round 4
// 263.642 us; speedup vs baseline: 2.0291x; 1.3288x over previous
//
#include <hip/hip_runtime.h>
#include <cmath>

#define N_NODES 50000
#define N_EDGES 800000
#define N_FEAT 128
#define DIM 64
#define N_GRAPHS 512
#define SCAN_NBLK ((N_NODES + 255) / 256)   // 196
#define EGRID ((N_EDGES + 255) / 256)       // 3125
#define GGRID ((N_NODES + 63) / 64)         // 782

// ---------------------------------------------------------------------------
__global__ __launch_bounds__(256) void zero_i(int* __restrict__ p, int n) {
  int i = blockIdx.x * 256 + threadIdx.x;
  if (i < n) p[i] = 0;
}

// CSR build: histogram of dst
__global__ __launch_bounds__(256) void hist_dst(const int* __restrict__ dst,
                                                int* __restrict__ deg) {
  int e = blockIdx.x * 256 + threadIdx.x;
  if (e < N_EDGES) atomicAdd(&deg[dst[e]], 1);
}

// hierarchical exclusive scan: deg -> row_ptr[N+1], fill_pos
__global__ __launch_bounds__(256) void partial_sums(const int* __restrict__ deg,
                                                    int* __restrict__ partials) {
  __shared__ int ws[4];
  int gid = blockIdx.x * 256 + threadIdx.x;
  int v = (gid < N_NODES) ? deg[gid] : 0;
#pragma unroll
  for (int off = 32; off; off >>= 1) v += __shfl_down(v, off, 64);
  int lane = threadIdx.x & 63, w = threadIdx.x >> 6;
  if (lane == 0) ws[w] = v;
  __syncthreads();
  if (threadIdx.x == 0)
    partials[blockIdx.x] = ws[0] + ws[1] + ws[2] + ws[3];
}

__global__ __launch_bounds__(256) void scan_partials(int* __restrict__ partials) {
  __shared__ int buf[256];
  int tid = threadIdx.x;
  int v = (tid < SCAN_NBLK) ? partials[tid] : 0;
  buf[tid] = v;
  __syncthreads();
  for (int off = 1; off < 256; off <<= 1) {
    int t = (tid >= off) ? buf[tid - off] : 0;
    __syncthreads();
    buf[tid] += t;
    __syncthreads();
  }
  if (tid < SCAN_NBLK) partials[tid] = buf[tid] - v;   // exclusive
}

__global__ __launch_bounds__(256) void scan_blocks(const int* __restrict__ deg,
                                                   const int* __restrict__ partials,
                                                   int* __restrict__ row_ptr,
                                                   int* __restrict__ fill_pos) {
  __shared__ int buf[256];
  int tid = threadIdx.x;
  int gid = blockIdx.x * 256 + tid;
  int v = (gid < N_NODES) ? deg[gid] : 0;
  buf[tid] = v;
  __syncthreads();
  for (int off = 1; off < 256; off <<= 1) {
    int t = (tid >= off) ? buf[tid - off] : 0;
    __syncthreads();
    buf[tid] += t;
    __syncthreads();
  }
  int excl = buf[tid] - v + partials[blockIdx.x];
  if (gid <= N_NODES) {
    row_ptr[gid] = excl;
    if (gid < N_NODES) fill_pos[gid] = excl;
  }
}

// ---------------------------------------------------------------------------
// GEMM body: out[M][64] = act(A[M][K]) @ W[K][64].
// sX staged in K-chunks of 32 (64x36 = 9.2KB), sW in 64-row chunks (16KB):
// 25.6KB LDS -> 6 blocks/CU (vs 50KB -> 3) for latency hiding.
template<int K, bool RELU>
__device__ __forceinline__ void gemm_body(const float* __restrict__ A,
                                          const float* __restrict__ W,
                                          float* __restrict__ out, int M,
                                          int row0, int tid,
                                          float* sX, float* sW) {
  const int tx = tid & 15, ty = tid >> 4;
  const int q = tid & 7, r0 = tid >> 3;
  float acc[4][4] = {};

  for (int kb = 0; kb < K; kb += 32) {
    __syncthreads();
    if ((kb & 63) == 0) {
#pragma unroll
      for (int i = 0; i < 16; i++)
        sW[i * 256 + tid] = W[kb * 64 + i * 256 + tid];
    }
#pragma unroll
    for (int rr = 0; rr < 64; rr += 32) {
      int r = r0 + rr;
      int gr = row0 + r;
      float4 v = make_float4(0.f, 0.f, 0.f, 0.f);
      if (gr < M) v = *(const float4*)&A[(size_t)gr * K + kb + q * 4];
      if (RELU) {
        v.x = fmaxf(v.x, 0.f); v.y = fmaxf(v.y, 0.f);
        v.z = fmaxf(v.z, 0.f); v.w = fmaxf(v.w, 0.f);
      }
      *(float4*)&sX[r * 36 + q * 4] = v;
    }
    __syncthreads();

    const int kw = kb & 63;
#pragma unroll 4
    for (int k = 0; k < 32; k += 4) {
      float4 wv[4];
#pragma unroll
      for (int kk = 0; kk < 4; kk++)
        wv[kk] = *(const float4*)&sW[(kw + k + kk) * 64 + tx * 4];
#pragma unroll
      for (int r = 0; r < 4; r++) {
        float4 xv = *(const float4*)&sX[(ty * 4 + r) * 36 + k];
        const float xs[4] = {xv.x, xv.y, xv.z, xv.w};
#pragma unroll
        for (int kk = 0; kk < 4; kk++) {
          acc[r][0] += xs[kk] * wv[kk].x;
          acc[r][1] += xs[kk] * wv[kk].y;
          acc[r][2] += xs[kk] * wv[kk].z;
          acc[r][3] += xs[kk] * wv[kk].w;
        }
      }
    }
  }

#pragma unroll
  for (int r = 0; r < 4; r++) {
    int gr = row0 + ty * 4 + r;
    if (gr < M)
      *(float4*)&out[(size_t)gr * 64 + tx * 4] =
          make_float4(acc[r][0], acc[r][1], acc[r][2], acc[r][3]);
  }
}

// fused: blocks [0,GGRID) run gemm1 (x@W1 -> h); blocks [GGRID,+EGRID) run
// fill_csr. Independent work, one dispatch -> overlap the 52us scatter.
__global__ __launch_bounds__(256) void gemm1_fill(const float* __restrict__ x,
                                                  const float* __restrict__ W1,
                                                  float* __restrict__ h,
                                                  const int* __restrict__ src,
                                                  const int* __restrict__ dst,
                                                  int* __restrict__ fill_pos,
                                                  int* __restrict__ col) {
  __shared__ float sX[64 * 36];
  __shared__ float sW[64 * 64];
  if (blockIdx.x < GGRID) {
    gemm_body<N_FEAT, false>(x, W1, h, N_NODES, blockIdx.x * 64, threadIdx.x, sX, sW);
  } else {
    int e = (blockIdx.x - GGRID) * 256 + threadIdx.x;
    if (e < N_EDGES) {
      int slot = atomicAdd(&fill_pos[dst[e]], 1);
      col[slot] = src[e];
    }
  }
}

template<int K, bool RELU>
__global__ __launch_bounds__(256) void gemm_n64(const float* __restrict__ A,
                                                const float* __restrict__ W,
                                                float* __restrict__ out, int M) {
  __shared__ float sX[64 * 36];
  __shared__ float sW[64 * 64];
  gemm_body<K, RELU>(A, W, out, M, blockIdx.x * 64, threadIdx.x, sX, sW);
}

// ---------------------------------------------------------------------------
// gather v2: wave per node; lane = (edge-offset eo 0..3, feature-quad qf).
// One float4 load per lane per 4-edge group; xor-shuffle reduce across eo.
__global__ __launch_bounds__(256) void gather_sum(const float* __restrict__ h,
                                                  const int* __restrict__ row_ptr,
                                                  const int* __restrict__ col,
                                                  float* __restrict__ out) {
  int node = blockIdx.x * 4 + (threadIdx.x >> 6);
  if (node >= N_NODES) return;
  int lane = threadIdx.x & 63;
  int eo = lane >> 4;
  int qf = (lane & 15) << 2;
  int i = row_ptr[node];
  const int end = row_ptr[node + 1];

  float4 acc = make_float4(0.f, 0.f, 0.f, 0.f);
  for (; i + 8 <= end; i += 8) {
    int s0 = col[i + eo];
    int s1 = col[i + 4 + eo];
    float4 v0 = *(const float4*)&h[(size_t)s0 * 64 + qf];
    float4 v1 = *(const float4*)&h[(size_t)s1 * 64 + qf];
    acc.x += v0.x + v1.x; acc.y += v0.y + v1.y;
    acc.z += v0.z + v1.z; acc.w += v0.w + v1.w;
  }
  for (; i + 4 <= end; i += 4) {
    int s = col[i + eo];
    float4 v = *(const float4*)&h[(size_t)s * 64 + qf];
    acc.x += v.x; acc.y += v.y; acc.z += v.z; acc.w += v.w;
  }
  if (eo < end - i) {
    int s = col[i + eo];
    float4 v = *(const float4*)&h[(size_t)s * 64 + qf];
    acc.x += v.x; acc.y += v.y; acc.z += v.z; acc.w += v.w;
  }
#pragma unroll
  for (int m = 16; m <= 32; m <<= 1) {
    acc.x += __shfl_xor(acc.x, m, 64);
    acc.y += __shfl_xor(acc.y, m, 64);
    acc.z += __shfl_xor(acc.z, m, 64);
    acc.w += __shfl_xor(acc.w, m, 64);
  }
  if (eo == 0) *(float4*)&out[(size_t)node * 64 + qf] = acc;
}

// ---------------------------------------------------------------------------
// batch is SORTED -> contiguous segment per graph. 4 waves split the rows.
__global__ __launch_bounds__(256) void pool_fc(const float* __restrict__ agg,
                                               const int* __restrict__ batch,
                                               const float* __restrict__ Wfc,
                                               float* __restrict__ out) {
  __shared__ float sacc[4][64];
  int g = blockIdx.x;
  int tid = threadIdx.x, lane = tid & 63, w = tid >> 6;

  int lo = 0, hi = N_NODES;
  while (lo < hi) { int mid = (lo + hi) >> 1; if (batch[mid] < g) lo = mid + 1; else hi = mid; }
  const int start = lo;
  hi = N_NODES;
  while (lo < hi) { int mid = (lo + hi) >> 1; if (batch[mid] < g + 1) lo = mid + 1; else hi = mid; }
  const int end = lo;

  float acc = 0.f;
  for (int n = start + w; n < end; n += 4) acc += agg[(size_t)n * 64 + lane];
  sacc[w][lane] = acc;
  __syncthreads();
  if (w == 0) {
    float v = sacc[0][lane] + sacc[1][lane] + sacc[2][lane] + sacc[3][lane];
    v /= fmaxf((float)(end - start), 1.f);
    v *= Wfc[lane];
#pragma unroll
    for (int off = 32; off; off >>= 1) v += __shfl_down(v, off, 64);
    if (lane == 0) out[g] = 1.f / (1.f + expf(-v));
  }
}

// ---------------------------------------------------------------------------
extern "C" void kernel_launch(void* const* d_in, const int* in_sizes, int n_in,
                              void* d_out, int out_size, void* d_ws, size_t ws_size,
                              hipStream_t stream) {
  const float* x     = (const float*)d_in[0];
  const int*   ei    = (const int*)d_in[1];   // [2, E]: src then dst
  const int*   batch = (const int*)d_in[2];
  const float* W1    = (const float*)d_in[3];
  const float* W2    = (const float*)d_in[4];
  const float* Wfc   = (const float*)d_in[5];
  float*       out   = (float*)d_out;

  const int* src = ei;
  const int* dst = ei + N_EDGES;

  // workspace layout (~29.4 MB)
  char* ws = (char*)d_ws;
  float* h        = (float*)(ws);                                   // [N,64]
  float* agg      = (float*)(ws + (size_t)N_NODES * DIM * 4);       // [N,64]
  int*   deg      = (int*)  (ws + (size_t)N_NODES * DIM * 8);
  int*   row_ptr  = deg + N_NODES;
  int*   fill_pos = row_ptr + N_NODES + 1;
  int*   col      = fill_pos + N_NODES;                             // [E]
  int*   partials = col + N_EDGES;                                  // [196]

  const int ngrid4 = (N_NODES + 3) / 4;

  // CSR build front half (shared by both layers)
  zero_i<<<SCAN_NBLK, 256, 0, stream>>>(deg, N_NODES);
  hist_dst<<<EGRID, 256, 0, stream>>>(dst, deg);
  partial_sums<<<SCAN_NBLK, 256, 0, stream>>>(deg, partials);
  scan_partials<<<1, 256, 0, stream>>>(partials);
  scan_blocks<<<SCAN_NBLK, 256, 0, stream>>>(deg, partials, row_ptr, fill_pos);

  // fill_csr || gemm1 (independent): h = x @ W1, col[] built
  gemm1_fill<<<GGRID + EGRID, 256, 0, stream>>>(x, W1, h, src, dst, fill_pos, col);

  // layer 1 aggregate
  gather_sum<<<ngrid4, 256, 0, stream>>>(h, row_ptr, col, agg);

  // layer 2: h = relu(agg) @ W2 ; agg = gather_sum(h)
  gemm_n64<DIM, true><<<GGRID, 256, 0, stream>>>(agg, W2, h, N_NODES);
  gather_sum<<<ngrid4, 256, 0, stream>>>(h, row_ptr, col, agg);

  // mean-pool per graph + FC + sigmoid
  pool_fc<<<N_GRAPHS, 256, 0, stream>>>(agg, batch, Wfc, out);
}